// Round 8
// baseline (76.363 us; speedup 1.0000x reference)
//
#include <hip/hip_runtime.h>

// GaussianMask: K[b,c,k,h,w] = exp(-(Xnbr - Xctr)^2 / 2), bw=1
// X: (4,3,512,512) fp32. Out: (4,3,24,512,512) fp32. Zero padding, center skipped.
// Write-BW-bound: 302 MB out vs 12.6 MB in.
// R8: exact R5 structure (k = blockIdx.y, 1 quad/thread, 295K waves) but with
//     PLAIN stores instead of nontemporal: each line is written once and
//     plane-sequentially, so L2 write-combining (fill kernel hits 7.0 TB/s with
//     normal stores) should beat NT's direct-to-HBM path. A/B vs R5's 53.8us.

#define HH 512
#define WW 512
#define NPLANES 12   // B*C
#define NK 24
#define HW (HH * WW)

typedef float f32x4 __attribute__((ext_vector_type(4)));

extern "C" __device__ float __builtin_amdgcn_exp2f(float);

template <int DR, int DC>
__device__ __forceinline__ void do_case(const float* __restrict__ Xp,
                                        float* __restrict__ kp,
                                        int h, int w0)
{
    const float c = -0.5f * 1.44269504088896340736f;  // -0.5*log2(e)
    const float* ctr_row = Xp + (size_t)h * WW;
    const f32x4 xc = *reinterpret_cast<const f32x4*>(ctr_row + w0);

    const int hh = h + DR - 2;
    f32x4 nb;
    if (hh >= 0 && hh < HH) {                    // wave-uniform (64 lanes share h)
        const float* nr = Xp + (size_t)hh * WW;
        if constexpr (DC == 2) {
            nb = *reinterpret_cast<const f32x4*>(nr + w0);
        } else if constexpr (DC < 2) {
            const f32x4 qC = *reinterpret_cast<const f32x4*>(nr + w0);
            const f32x4 qA = *reinterpret_cast<const f32x4*>(nr + (w0 > 0 ? w0 - 4 : 0));
            constexpr int off = DC - 2;          // -2 or -1
            #pragma unroll
            for (int i = 0; i < 4; ++i) {
                float v;
                if (off + i < 0) {               // compile-time per i
                    v = (w0 > 0) ? qA[4 + off + i] : 0.0f;
                } else {
                    v = qC[off + i];
                }
                nb[i] = v;
            }
        } else {                                 // DC > 2
            const f32x4 qC = *reinterpret_cast<const f32x4*>(nr + w0);
            const f32x4 qB = *reinterpret_cast<const f32x4*>(nr + (w0 < WW - 4 ? w0 + 4 : WW - 4));
            constexpr int off = DC - 2;          // 1 or 2
            #pragma unroll
            for (int i = 0; i < 4; ++i) {
                float v;
                if (off + i > 3) {               // compile-time per i
                    v = (w0 < WW - 4) ? qB[off + i - 4] : 0.0f;
                } else {
                    v = qC[off + i];
                }
                nb[i] = v;
            }
        }
    } else {
        #pragma unroll
        for (int i = 0; i < 4; ++i) nb[i] = 0.0f;   // zero padding row
    }

    f32x4 v;
    #pragma unroll
    for (int i = 0; i < 4; ++i) {
        const float d = nb[i] - xc[i];
        v[i] = __builtin_amdgcn_exp2f(d * d * c);
    }
    *reinterpret_cast<f32x4*>(kp + (size_t)h * WW + w0) = v;   // plain store (L2-buffered)
}

__global__ __launch_bounds__(512) void gauss_mask_kernel(
    const float* __restrict__ X, float* __restrict__ out)
{
    // blockIdx.x covers (p,h,w0) quads; blockIdx.y = k (compile-time dr,dc)
    const int idx = blockIdx.x * 512 + threadIdx.x;   // [0, 786432)
    const int p   = idx >> 16;            // 65536 quads per plane
    const int rem = idx & 65535;
    const int h   = rem >> 7;
    const int w0  = (rem & 127) << 2;
    const int k   = blockIdx.y;

    const float* Xp = X + (size_t)p * HW;
    float* kp = out + ((size_t)p * NK + k) * HW;

    switch (k) {
        case  0: do_case<0, 0>(Xp, kp, h, w0); break;
        case  1: do_case<0, 1>(Xp, kp, h, w0); break;
        case  2: do_case<0, 2>(Xp, kp, h, w0); break;
        case  3: do_case<0, 3>(Xp, kp, h, w0); break;
        case  4: do_case<0, 4>(Xp, kp, h, w0); break;
        case  5: do_case<1, 0>(Xp, kp, h, w0); break;
        case  6: do_case<1, 1>(Xp, kp, h, w0); break;
        case  7: do_case<1, 2>(Xp, kp, h, w0); break;
        case  8: do_case<1, 3>(Xp, kp, h, w0); break;
        case  9: do_case<1, 4>(Xp, kp, h, w0); break;
        case 10: do_case<2, 0>(Xp, kp, h, w0); break;
        case 11: do_case<2, 1>(Xp, kp, h, w0); break;
        case 12: do_case<2, 3>(Xp, kp, h, w0); break;
        case 13: do_case<2, 4>(Xp, kp, h, w0); break;
        case 14: do_case<3, 0>(Xp, kp, h, w0); break;
        case 15: do_case<3, 1>(Xp, kp, h, w0); break;
        case 16: do_case<3, 2>(Xp, kp, h, w0); break;
        case 17: do_case<3, 3>(Xp, kp, h, w0); break;
        case 18: do_case<3, 4>(Xp, kp, h, w0); break;
        case 19: do_case<4, 0>(Xp, kp, h, w0); break;
        case 20: do_case<4, 1>(Xp, kp, h, w0); break;
        case 21: do_case<4, 2>(Xp, kp, h, w0); break;
        case 22: do_case<4, 3>(Xp, kp, h, w0); break;
        case 23: do_case<4, 4>(Xp, kp, h, w0); break;
    }
}

extern "C" void kernel_launch(void* const* d_in, const int* in_sizes, int n_in,
                              void* d_out, int out_size, void* d_ws, size_t ws_size,
                              hipStream_t stream) {
    const float* X = (const float*)d_in[0];
    float* out = (float*)d_out;

    // per k: 12 planes * 512 * 128 quads = 786432 threads / 512 = 1536 blocks
    dim3 grid(1536, NK);
    gauss_mask_kernel<<<grid, 512, 0, stream>>>(X, out);
}

// Round 9
// 73.089 us; speedup vs baseline: 1.0448x; 1.0448x over previous
//
#include <hip/hip_runtime.h>

// GaussianMask: K[b,c,k,h,w] = exp(-(Xnbr - Xctr)^2 / 2), bw=1
// X: (4,3,512,512) fp32. Out: (4,3,24,512,512) fp32. Zero padding, center skipped.
// Write-BW-bound: 302 MB out vs 12.6 MB in.
// R8: exact R5 structure (k = blockIdx.y, 1 quad/thread, 295K waves) but with
//     PLAIN stores instead of nontemporal: each line is written once and
//     plane-sequentially, so L2 write-combining (fill kernel hits 7.0 TB/s with
//     normal stores) should beat NT's direct-to-HBM path. A/B vs R5's 53.8us.

#define HH 512
#define WW 512
#define NPLANES 12   // B*C
#define NK 24
#define HW (HH * WW)

typedef float f32x4 __attribute__((ext_vector_type(4)));

extern "C" __device__ float __builtin_amdgcn_exp2f(float);

template <int DR, int DC>
__device__ __forceinline__ void do_case(const float* __restrict__ Xp,
                                        float* __restrict__ kp,
                                        int h, int w0)
{
    const float c = -0.5f * 1.44269504088896340736f;  // -0.5*log2(e)
    const float* ctr_row = Xp + (size_t)h * WW;
    const f32x4 xc = *reinterpret_cast<const f32x4*>(ctr_row + w0);

    const int hh = h + DR - 2;
    f32x4 nb;
    if (hh >= 0 && hh < HH) {                    // wave-uniform (64 lanes share h)
        const float* nr = Xp + (size_t)hh * WW;
        if constexpr (DC == 2) {
            nb = *reinterpret_cast<const f32x4*>(nr + w0);
        } else if constexpr (DC < 2) {
            const f32x4 qC = *reinterpret_cast<const f32x4*>(nr + w0);
            const f32x4 qA = *reinterpret_cast<const f32x4*>(nr + (w0 > 0 ? w0 - 4 : 0));
            constexpr int off = DC - 2;          // -2 or -1
            #pragma unroll
            for (int i = 0; i < 4; ++i) {
                float v;
                if (off + i < 0) {               // compile-time per i
                    v = (w0 > 0) ? qA[4 + off + i] : 0.0f;
                } else {
                    v = qC[off + i];
                }
                nb[i] = v;
            }
        } else {                                 // DC > 2
            const f32x4 qC = *reinterpret_cast<const f32x4*>(nr + w0);
            const f32x4 qB = *reinterpret_cast<const f32x4*>(nr + (w0 < WW - 4 ? w0 + 4 : WW - 4));
            constexpr int off = DC - 2;          // 1 or 2
            #pragma unroll
            for (int i = 0; i < 4; ++i) {
                float v;
                if (off + i > 3) {               // compile-time per i
                    v = (w0 < WW - 4) ? qB[off + i - 4] : 0.0f;
                } else {
                    v = qC[off + i];
                }
                nb[i] = v;
            }
        }
    } else {
        #pragma unroll
        for (int i = 0; i < 4; ++i) nb[i] = 0.0f;   // zero padding row
    }

    f32x4 v;
    #pragma unroll
    for (int i = 0; i < 4; ++i) {
        const float d = nb[i] - xc[i];
        v[i] = __builtin_amdgcn_exp2f(d * d * c);
    }
    *reinterpret_cast<f32x4*>(kp + (size_t)h * WW + w0) = v;   // plain store (L2-buffered)
}

__global__ __launch_bounds__(512) void gauss_mask_kernel(
    const float* __restrict__ X, float* __restrict__ out)
{
    // blockIdx.x covers (p,h,w0) quads; blockIdx.y = k (compile-time dr,dc)
    const int idx = blockIdx.x * 512 + threadIdx.x;   // [0, 786432)
    const int p   = idx >> 16;            // 65536 quads per plane
    const int rem = idx & 65535;
    const int h   = rem >> 7;
    const int w0  = (rem & 127) << 2;
    const int k   = blockIdx.y;

    const float* Xp = X + (size_t)p * HW;
    float* kp = out + ((size_t)p * NK + k) * HW;

    switch (k) {
        case  0: do_case<0, 0>(Xp, kp, h, w0); break;
        case  1: do_case<0, 1>(Xp, kp, h, w0); break;
        case  2: do_case<0, 2>(Xp, kp, h, w0); break;
        case  3: do_case<0, 3>(Xp, kp, h, w0); break;
        case  4: do_case<0, 4>(Xp, kp, h, w0); break;
        case  5: do_case<1, 0>(Xp, kp, h, w0); break;
        case  6: do_case<1, 1>(Xp, kp, h, w0); break;
        case  7: do_case<1, 2>(Xp, kp, h, w0); break;
        case  8: do_case<1, 3>(Xp, kp, h, w0); break;
        case  9: do_case<1, 4>(Xp, kp, h, w0); break;
        case 10: do_case<2, 0>(Xp, kp, h, w0); break;
        case 11: do_case<2, 1>(Xp, kp, h, w0); break;
        case 12: do_case<2, 3>(Xp, kp, h, w0); break;
        case 13: do_case<2, 4>(Xp, kp, h, w0); break;
        case 14: do_case<3, 0>(Xp, kp, h, w0); break;
        case 15: do_case<3, 1>(Xp, kp, h, w0); break;
        case 16: do_case<3, 2>(Xp, kp, h, w0); break;
        case 17: do_case<3, 3>(Xp, kp, h, w0); break;
        case 18: do_case<3, 4>(Xp, kp, h, w0); break;
        case 19: do_case<4, 0>(Xp, kp, h, w0); break;
        case 20: do_case<4, 1>(Xp, kp, h, w0); break;
        case 21: do_case<4, 2>(Xp, kp, h, w0); break;
        case 22: do_case<4, 3>(Xp, kp, h, w0); break;
        case 23: do_case<4, 4>(Xp, kp, h, w0); break;
    }
}

extern "C" void kernel_launch(void* const* d_in, const int* in_sizes, int n_in,
                              void* d_out, int out_size, void* d_ws, size_t ws_size,
                              hipStream_t stream) {
    const float* X = (const float*)d_in[0];
    float* out = (float*)d_out;

    // per k: 12 planes * 512 * 128 quads = 786432 threads / 512 = 1536 blocks
    dim3 grid(1536, NK);
    gauss_mask_kernel<<<grid, 512, 0, stream>>>(X, out);
}

// Round 10
// 53.186 us; speedup vs baseline: 1.4358x; 1.3742x over previous
//
#include <hip/hip_runtime.h>

// GaussianMask: K[b,c,k,h,w] = exp(-(Xnbr - Xctr)^2 / 2), bw=1
// X: (4,3,512,512) fp32. Out: (4,3,24,512,512) fp32. Zero padding, center skipped.
// Write-BW-bound: 302 MB out (NT stores) vs 12.6 MB in (L2/L3-hot).
// R10: R5 structure (k = blockIdx.y, 1 quad/thread, NT stores) with minimized
//      per-thread VALU: p/rem decomposed on SALU, all indices int32, neighbor
//      row + halo quads addressed as compile-time offsets from ONE voffset
//      (SGPR-base + voffset + imm), border handling via value cndmask.

#define HH 512
#define WW 512
#define NK 24
#define HW (HH * WW)

typedef float f32x4 __attribute__((ext_vector_type(4)));

extern "C" __device__ float __builtin_amdgcn_exp2f(float);

template <int DR, int DC>
__device__ __forceinline__ void do_case(const float* __restrict__ Xp,
                                        float* __restrict__ kp,
                                        int rem /* quad index in plane [0,65536) */)
{
    const float c = -0.5f * 1.44269504088896340736f;  // -0.5*log2(e)
    const int wcol = rem & 127;         // quad column
    const int ci   = rem << 2;          // center element index (int32)

    const f32x4 xc = *reinterpret_cast<const f32x4*>(Xp + ci);

    f32x4 nb;
    const int h  = rem >> 7;            // wave-uniform (64 lanes span half a row)
    const int hh = h + DR - 2;
    if ((DR == 2) || (hh >= 0 && hh < HH)) {   // wave-uniform branch
        const int ni = ci + (DR - 2) * WW;     // neighbor row, same quad: imm offset
        if constexpr (DC == 2) {
            nb = *reinterpret_cast<const f32x4*>(Xp + ni);
        } else if constexpr (DC < 2) {
            const bool wl = (wcol > 0);
            const f32x4 qC = *reinterpret_cast<const f32x4*>(Xp + ni);
            const f32x4 qA = *reinterpret_cast<const f32x4*>(Xp + ni + (wl ? -4 : 0));
            const float A2 = wl ? qA[2] : 0.0f;
            const float A3 = wl ? qA[3] : 0.0f;
            if constexpr (DC == 0) {
                nb[0] = A2; nb[1] = A3; nb[2] = qC[0]; nb[3] = qC[1];
            } else {
                nb[0] = A3; nb[1] = qC[0]; nb[2] = qC[1]; nb[3] = qC[2];
            }
        } else {
            const bool wr = (wcol < 127);
            const f32x4 qC = *reinterpret_cast<const f32x4*>(Xp + ni);
            const f32x4 qB = *reinterpret_cast<const f32x4*>(Xp + ni + (wr ? 4 : 0));
            const float B0 = wr ? qB[0] : 0.0f;
            const float B1 = wr ? qB[1] : 0.0f;
            if constexpr (DC == 3) {
                nb[0] = qC[1]; nb[1] = qC[2]; nb[2] = qC[3]; nb[3] = B0;
            } else {
                nb[0] = qC[2]; nb[1] = qC[3]; nb[2] = B0; nb[3] = B1;
            }
        }
    } else {
        nb[0] = nb[1] = nb[2] = nb[3] = 0.0f;   // zero-padded row
    }

    f32x4 v;
    #pragma unroll
    for (int i = 0; i < 4; ++i) {
        const float d = nb[i] - xc[i];
        v[i] = __builtin_amdgcn_exp2f(d * d * c);
    }
    __builtin_nontemporal_store(v, reinterpret_cast<f32x4*>(kp + ci));
}

__global__ __launch_bounds__(512) void gauss_mask_kernel(
    const float* __restrict__ X, float* __restrict__ out)
{
    // 128 blocks per plane (block-uniform p), blockIdx.y = k (compile-time dr,dc)
    const int p   = blockIdx.x >> 7;                         // SALU
    const int rem = ((blockIdx.x & 127) << 9) | threadIdx.x; // quad idx in plane
    const int k   = blockIdx.y;

    const float* Xp = X + (size_t)p * HW;
    float* kp = out + ((size_t)p * NK + k) * HW;

    switch (k) {
        case  0: do_case<0, 0>(Xp, kp, rem); break;
        case  1: do_case<0, 1>(Xp, kp, rem); break;
        case  2: do_case<0, 2>(Xp, kp, rem); break;
        case  3: do_case<0, 3>(Xp, kp, rem); break;
        case  4: do_case<0, 4>(Xp, kp, rem); break;
        case  5: do_case<1, 0>(Xp, kp, rem); break;
        case  6: do_case<1, 1>(Xp, kp, rem); break;
        case  7: do_case<1, 2>(Xp, kp, rem); break;
        case  8: do_case<1, 3>(Xp, kp, rem); break;
        case  9: do_case<1, 4>(Xp, kp, rem); break;
        case 10: do_case<2, 0>(Xp, kp, rem); break;
        case 11: do_case<2, 1>(Xp, kp, rem); break;
        case 12: do_case<2, 3>(Xp, kp, rem); break;
        case 13: do_case<2, 4>(Xp, kp, rem); break;
        case 14: do_case<3, 0>(Xp, kp, rem); break;
        case 15: do_case<3, 1>(Xp, kp, rem); break;
        case 16: do_case<3, 2>(Xp, kp, rem); break;
        case 17: do_case<3, 3>(Xp, kp, rem); break;
        case 18: do_case<3, 4>(Xp, kp, rem); break;
        case 19: do_case<4, 0>(Xp, kp, rem); break;
        case 20: do_case<4, 1>(Xp, kp, rem); break;
        case 21: do_case<4, 2>(Xp, kp, rem); break;
        case 22: do_case<4, 3>(Xp, kp, rem); break;
        case 23: do_case<4, 4>(Xp, kp, rem); break;
    }
}

extern "C" void kernel_launch(void* const* d_in, const int* in_sizes, int n_in,
                              void* d_out, int out_size, void* d_ws, size_t ws_size,
                              hipStream_t stream) {
    const float* X = (const float*)d_in[0];
    float* out = (float*)d_out;

    // per k: 12 planes * 128 blocks = 1536 blocks of 512 threads
    dim3 grid(1536, NK);
    gauss_mask_kernel<<<grid, 512, 0, stream>>>(X, out);
}